// Round 11
// baseline (286.377 us; speedup 1.0000x reference)
//
#include <hip/hip_runtime.h>
#include <hip/hip_fp16.h>
#include <cstdint>
#include <cstddef>

// Problem constants (fixed by reference)
#define NB      64      // batch
#define NBITS   4096
#define HD      64      // hidden
#define IN_DIM  4098
#define LMAXT   320
#define SEQ_STRIDE 336  // padded seq row (>= LMAX+2, mult of 16)
#define NTILE   257     // col tiles of 16 (4112 padded cols)
#define LOG2E   1.44269504088896340f
#define TWO_L2E 2.88539008177792680f
#define CSPLIT  8       // column-split waves per k_proj block
#define NBLK_PROJ 640

// Workspace layout (bytes)
static constexpr size_t SEQ_OFF    = 0;                              // 86016
static constexpr size_t STEPS_OFF  = 86016;                          // 256
static constexpr size_t LOSS_OFF   = 86272;                          // 4
static constexpr size_t TICKET_OFF = 86276;                          // 4
static constexpr size_t XB_OFF     = 86528;                          // 64*320*64*2
static constexpr size_t WB_OFF     = XB_OFF + 2621440;               // 257*1024*2
static constexpr size_t BO_OFF     = WB_OFF + 526336;                // 4112*4

typedef float     f32x4  __attribute__((ext_vector_type(4)));
typedef _Float16  h2     __attribute__((ext_vector_type(2)));
typedef _Float16  h8     __attribute__((ext_vector_type(8)));

#if __has_builtin(__builtin_amdgcn_fdot2)
#define FDOT2(a, b, c) __builtin_amdgcn_fdot2((a), (b), (c), false)
#else
#define FDOT2(a, b, c) fmaf((float)(a)[0], (float)(b)[0], \
                        fmaf((float)(a)[1], (float)(b)[1], (c)))
#endif

// glibc's math.h macro-expands a declaration named __exp2f -> do NOT use that
// identifier; go straight to the HW builtin (v_exp_f32).
__device__ __forceinline__ float ex2(float x) {
#if __has_builtin(__builtin_amdgcn_exp2f)
  return __builtin_amdgcn_exp2f(x);
#else
  return __expf(x * 0.6931471805599453f);
#endif
}
__device__ __forceinline__ float frcp(float x) {
#if __has_builtin(__builtin_amdgcn_rcpf)
  return __builtin_amdgcn_rcpf(x);
#else
  return 1.f / x;
#endif
}

__device__ __forceinline__ unsigned short f2h(float f) {
  return __builtin_bit_cast(unsigned short, (_Float16)f);
}
__device__ __forceinline__ float h2f(unsigned short u) {
  return (float)__builtin_bit_cast(_Float16, u);
}
__device__ __forceinline__ h8 ldh8(const unsigned short* p) {
  return *(const h8*)p;
}
__device__ __forceinline__ void wave_lds_fence() {
  __asm__ __volatile__("s_waitcnt lgkmcnt(0)" ::: "memory");
}

// ---------------------------------------------------------------------------
// Kernel A (merged): blocks 0..63 = per-row compaction (wave 0 only);
// blocks 64..320 = f16 fragment-major W tiles + pre-scaled shifted bias.
// Block 0 also zeroes the loss accumulator and the k_proj finish ticket.
// ---------------------------------------------------------------------------
__global__ __launch_bounds__(256) void k_setup_prep(
    const float* __restrict__ true_fp, const int* __restrict__ perm,
    const float* __restrict__ W_out, const float* __restrict__ b_out,
    int* __restrict__ seq, int* __restrict__ steps,
    unsigned short* __restrict__ Wh, float* __restrict__ bo2,
    float* __restrict__ loss_accum, int* __restrict__ ticket) {
  __shared__ unsigned long long bits[64];
  const int blk = blockIdx.x;

  if (blk < NB) {
    // ---- compaction for batch row blk (single wave) ----
    if (threadIdx.x >= 64) return;
    const int b = blk;
    const int j = threadIdx.x;
    if (b == 0 && j == 0) { *loss_accum = 0.f; *ticket = 0; }
    const float* row = true_fp + (size_t)b * NBITS;
    {
      const float4* rv = (const float4*)(row + j * 64);
      unsigned long long w = 0ull;
#pragma unroll
      for (int i = 0; i < 16; ++i) {
        const float4 v = rv[i];
        w |= (unsigned long long)(v.x > 0.f) << (4 * i + 0);
        w |= (unsigned long long)(v.y > 0.f) << (4 * i + 1);
        w |= (unsigned long long)(v.z > 0.f) << (4 * i + 2);
        w |= (unsigned long long)(v.w > 0.f) << (4 * i + 3);
      }
      bits[j] = w;
    }
    wave_lds_fence();

    int* srow = seq + b * SEQ_STRIDE;
    int base = 0;
    for (int c0 = 0; c0 < IN_DIM; c0 += 64) {
      const int col = c0 + j;
      bool pred = false;
      if (col < IN_DIM) {
        if (col == 0 || col == IN_DIM - 1) pred = true;
        else {
          const int p = perm[col - 1];
          pred = (bits[p >> 6] >> (p & 63)) & 1ull;
        }
      }
      const unsigned long long mask = __ballot(pred);
      const int prefix = __popcll(mask & ((1ull << j) - 1ull));
      const int idx = base + prefix;
      if (pred && idx <= LMAXT) srow[idx] = col;
      base += __popcll(mask);
    }
    const int cap = (base <= LMAXT + 1) ? base : (LMAXT + 1);
    for (int i = cap + j; i < SEQ_STRIDE; i += 64) srow[i] = 0;
    if (j == 0) {
      int s = base - 1;
      if (s > LMAXT) s = LMAXT;
      steps[b] = s;
    }
  } else {
    // ---- W tile prep for col tile c ----
    const int c = blk - NB;              // 0..256
    const int t = threadIdx.x;
    const int m = t & 15;                // col within tile
    const int col = c * 16 + m;
    const bool cok = col < IN_DIM;
#pragma unroll
    for (int kp = 0; kp < 4; ++kp) {
      const int k = kp * 16 + (t >> 4);
      const float v = cok ? W_out[(size_t)k * IN_DIM + col] : 0.f;
      Wh[c * 1024 + m * 64 + k] = f2h(v);
    }
    if (t < 16) {
      const int cc = c * 16 + t;
      bo2[c * 16 + t] = (cc < IN_DIM) ? (b_out[cc] - 30.f) * LOG2E : -1e30f;
    }
  }
}

// ---------------------------------------------------------------------------
// Kernel B: GRU recurrence. ONE WAVE per batch row. R10 cadence model:
// step time ~= instr_count x ~4-5 cyc single-wave issue. Diet round: biases
// and log2e scales folded into the prefetched W_ih values (1 fma each at
// prefetch), gates = fma/ex2/rcp chains, Xb stored as f16 (reuses the LDS
// cvt -- kills the 4-instr bf16 round). Same-wave DS ops are FIFO-ordered,
// so no fences in the loop (verified R10: absmax 0 without them).
// ---------------------------------------------------------------------------
#define W_DEF(i) h2 wr##i, wz##i, wn##i;
#define W_INIT(i) {                                                  \
    const float* w0_ = W_hh + (size_t)(2 * (i)) * 192;               \
    const float* w1_ = W_hh + (size_t)(2 * (i) + 1) * 192;           \
    wr##i[0] = (_Float16)w0_[g];       wr##i[1] = (_Float16)w1_[g];  \
    wz##i[0] = (_Float16)w0_[64 + g];  wz##i[1] = (_Float16)w1_[64 + g]; \
    wn##i[0] = (_Float16)w0_[128 + g]; wn##i[1] = (_Float16)w1_[128 + g]; }

#define DOT8(i) {                                                         \
    const h8 v_ = hp8[i];                                                 \
    const h2 e0_ = __builtin_shufflevector(v_, v_, 0, 1);                 \
    const h2 e1_ = __builtin_shufflevector(v_, v_, 2, 3);                 \
    const h2 e2_ = __builtin_shufflevector(v_, v_, 4, 5);                 \
    const h2 e3_ = __builtin_shufflevector(v_, v_, 6, 7);                 \
    sr0 = FDOT2(e0_, wr##i##_0, sr0);  sr1 = FDOT2(e1_, wr##i##_1, sr1);  \
    sr0 = FDOT2(e2_, wr##i##_2, sr0);  sr1 = FDOT2(e3_, wr##i##_3, sr1);  \
    sz0 = FDOT2(e0_, wz##i##_0, sz0);  sz1 = FDOT2(e1_, wz##i##_1, sz1);  \
    sz0 = FDOT2(e2_, wz##i##_2, sz0);  sz1 = FDOT2(e3_, wz##i##_3, sz1);  \
    sn0 = FDOT2(e0_, wn##i##_0, sn0);  sn1 = FDOT2(e1_, wn##i##_1, sn1);  \
    sn0 = FDOT2(e2_, wn##i##_2, sn0);  sn1 = FDOT2(e3_, wn##i##_3, sn1); }

#define W_ALIAS(i8, a, b, c, d)                                           \
  const h2 wr##i8##_0 = wr##a, wr##i8##_1 = wr##b,                        \
           wr##i8##_2 = wr##c, wr##i8##_3 = wr##d;                        \
  const h2 wz##i8##_0 = wz##a, wz##i8##_1 = wz##b,                        \
           wz##i8##_2 = wz##c, wz##i8##_3 = wz##d;                        \
  const h2 wn##i8##_0 = wn##a, wn##i8##_1 = wn##b,                        \
           wn##i8##_2 = wn##c, wn##i8##_3 = wn##d;

__global__ __launch_bounds__(64)
__attribute__((amdgpu_waves_per_eu(1, 1)))
void k_gru(
    const float* __restrict__ embeds,
    const float* __restrict__ W_ih, const float* __restrict__ b_ih,
    const float* __restrict__ W_hh, const float* __restrict__ b_hh,
    const int* __restrict__ seq, const int* __restrict__ steps,
    unsigned short* __restrict__ Xh) {
  const int b = blockIdx.x;
  const int g = threadIdx.x;   // 0..63

  __shared__ __align__(16) _Float16 hl[HD];
  __shared__ int seqL[LMAXT + 2];
  for (int i = g; i < LMAXT + 2; i += 64) seqL[i] = seq[b * SEQ_STRIDE + i];

  // 96 named h2 registers: W_hh columns for unit g over k-pairs
  W_DEF(0)  W_DEF(1)  W_DEF(2)  W_DEF(3)  W_DEF(4)  W_DEF(5)  W_DEF(6)  W_DEF(7)
  W_DEF(8)  W_DEF(9)  W_DEF(10) W_DEF(11) W_DEF(12) W_DEF(13) W_DEF(14) W_DEF(15)
  W_DEF(16) W_DEF(17) W_DEF(18) W_DEF(19) W_DEF(20) W_DEF(21) W_DEF(22) W_DEF(23)
  W_DEF(24) W_DEF(25) W_DEF(26) W_DEF(27) W_DEF(28) W_DEF(29) W_DEF(30) W_DEF(31)
  W_INIT(0)  W_INIT(1)  W_INIT(2)  W_INIT(3)  W_INIT(4)  W_INIT(5)  W_INIT(6)  W_INIT(7)
  W_INIT(8)  W_INIT(9)  W_INIT(10) W_INIT(11) W_INIT(12) W_INIT(13) W_INIT(14) W_INIT(15)
  W_INIT(16) W_INIT(17) W_INIT(18) W_INIT(19) W_INIT(20) W_INIT(21) W_INIT(22) W_INIT(23)
  W_INIT(24) W_INIT(25) W_INIT(26) W_INIT(27) W_INIT(28) W_INIT(29) W_INIT(30) W_INIT(31)
  W_ALIAS(0, 0, 1, 2, 3)     W_ALIAS(1, 4, 5, 6, 7)
  W_ALIAS(2, 8, 9, 10, 11)   W_ALIAS(3, 12, 13, 14, 15)
  W_ALIAS(4, 16, 17, 18, 19) W_ALIAS(5, 20, 21, 22, 23)
  W_ALIAS(6, 24, 25, 26, 27) W_ALIAS(7, 28, 29, 30, 31)

  // pre-scaled bias terms (fold bias + log2e scale into the prefetch fma)
  const float br2  = (b_ih[g]       + b_hh[g])       * -LOG2E;
  const float bz2  = (b_ih[64 + g]  + b_hh[64 + g])  * -LOG2E;
  const float bn2  = b_ih[128 + g]  * TWO_L2E;
  const float bhn2 = b_hh[128 + g]  * TWO_L2E;
  const int nst = steps[b];

  float hself = embeds[b * HD + g];
  hl[g] = (_Float16)hself;

  unsigned short* xptr = Xh + (size_t)b * LMAXT * HD + g;

  // depth-4 named prefetch slots: pre-scaled W_ih contributions
  float p0r, p0z, p0n, p1r, p1z, p1n, p2r, p2z, p2n, p3r, p3z, p3n;
  {
    const float* r0 = W_ih + (size_t)seqL[0] * 192;
    p0r = fmaf(r0[g], -LOG2E, br2); p0z = fmaf(r0[64 + g], -LOG2E, bz2);
    p0n = fmaf(r0[128 + g], TWO_L2E, bn2);
    const float* r1 = W_ih + (size_t)seqL[1] * 192;
    p1r = fmaf(r1[g], -LOG2E, br2); p1z = fmaf(r1[64 + g], -LOG2E, bz2);
    p1n = fmaf(r1[128 + g], TWO_L2E, bn2);
    const float* r2 = W_ih + (size_t)seqL[2] * 192;
    p2r = fmaf(r2[g], -LOG2E, br2); p2z = fmaf(r2[64 + g], -LOG2E, bz2);
    p2n = fmaf(r2[128 + g], TWO_L2E, bn2);
    const float* r3 = W_ih + (size_t)seqL[3] * 192;
    p3r = fmaf(r3[g], -LOG2E, br2); p3z = fmaf(r3[64 + g], -LOG2E, bz2);
    p3n = fmaf(r3[128 + g], TWO_L2E, bn2);
  }

#define GSTEP(u) {                                                        \
    int nt_ = t + (u) + 4; nt_ = (nt_ <= LMAXT + 1) ? nt_ : (LMAXT + 1);  \
    const int sidx_ = seqL[nt_];                                          \
    const h8* hp8 = (const h8*)hl;                                        \
    float sr0 = 0.f, sr1 = 0.f, sz0 = 0.f, sz1 = 0.f, sn0 = 0.f, sn1 = 0.f; \
    DOT8(0) DOT8(1) DOT8(2) DOT8(3) DOT8(4) DOT8(5) DOT8(6) DOT8(7)       \
    const float rr = frcp(1.f + ex2(fmaf(sr0 + sr1, -LOG2E, p##u##r)));   \
    const float zz = frcp(1.f + ex2(fmaf(sz0 + sz1, -LOG2E, p##u##z)));   \
    const float g2 = fmaf(sn0 + sn1, TWO_L2E, bhn2);                      \
    const float q  = frcp(1.f + ex2(fmaf(rr, g2, p##u##n)));              \
    const float th = fmaf(-2.f, q, 1.f);                                  \
    const float hn = fmaf(zz, hself - th, th);                            \
    hself = hn;                                                           \
    const _Float16 hh = (_Float16)hn;                                     \
    hl[g] = hh;                                                           \
    xptr[(size_t)(t + (u)) * HD] = __builtin_bit_cast(unsigned short, hh);\
    const float* rw_ = W_ih + (size_t)sidx_ * 192;                        \
    p##u##r = fmaf(rw_[g], -LOG2E, br2);                                  \
    p##u##z = fmaf(rw_[64 + g], -LOG2E, bz2);                             \
    p##u##n = fmaf(rw_[128 + g], TWO_L2E, bn2); }

  const int ngroups = (nst + 3) >> 2;
  for (int tg = 0; tg < ngroups; ++tg) {
    const int t = tg * 4;
    GSTEP(0)
    GSTEP(1)
    GSTEP(2)
    GSTEP(3)
  }
#undef GSTEP

  // zero-fill padded rows (overwrites the <=3 garbage tail stores too)
  for (int i = nst * HD + g; i < LMAXT * HD; i += 64)
    Xh[(size_t)b * (LMAXT * HD) + i] = 0;
}

// ---------------------------------------------------------------------------
// Kernel C: MFMA f16 fused projection + logsumexp + NLL + fused finalize.
// 512 threads = 8 column-split waves per (b, 32-row chunk); grid 640.
// Last block (device ticket) divides by the step count and writes d_out.
// ---------------------------------------------------------------------------
__global__ __launch_bounds__(512) void k_proj(
    const unsigned short* __restrict__ Xh,
    const unsigned short* __restrict__ Wh,
    const float* __restrict__ bo2,
    const int* __restrict__ seq, const int* __restrict__ steps,
    const float* __restrict__ b_out,
    float* __restrict__ loss_accum, int* __restrict__ ticket,
    float* __restrict__ out) {
  const int l  = threadIdx.x & 63;
  const int wv = threadIdx.x >> 6;         // 0..7 column-split wave id
  const int b  = blockIdx.x / 10;
  const int t0 = (blockIdx.x % 10) * 32;
  const int nst = steps[b];
  const bool active = (t0 < nst);          // block-uniform

  __shared__ float spart[CSPLIT][32];
  __shared__ int lastblk;

  if (active) {
    const int lm = l & 15;
    const int q  = l >> 4;

    const unsigned short* xp0 = Xh + ((size_t)b * LMAXT + t0 + lm) * HD + q * 8;
    const h8 a00 = ldh8(xp0);
    const h8 a01 = ldh8(xp0 + 32);
    const h8 a10 = ldh8(xp0 + 16 * HD);
    const h8 a11 = ldh8(xp0 + 16 * HD + 32);

    float s[8];
#pragma unroll
    for (int i = 0; i < 8; ++i) s[i] = 0.f;

    const int ct0 = wv * 33;
    const int ct1 = (ct0 + 33 < NTILE) ? (ct0 + 33) : NTILE;   // wave 7: 26

    const unsigned short* wp = Wh + lm * 64 + q * 8;
    const float* bop = bo2 + lm;

    h8 b0 = ldh8(wp + (size_t)ct0 * 1024);
    h8 b1 = ldh8(wp + (size_t)ct0 * 1024 + 32);
    float bo = bop[ct0 * 16];
    for (int ct = ct0; ct < ct1; ++ct) {
      h8 nb0, nb1; float nbo;
      if (ct + 1 < ct1) {
        const unsigned short* wpn = wp + (size_t)(ct + 1) * 1024;
        nb0 = ldh8(wpn); nb1 = ldh8(wpn + 32); nbo = bop[(ct + 1) * 16];
      }
      f32x4 acc0 = {0.f, 0.f, 0.f, 0.f};
      f32x4 acc1 = {0.f, 0.f, 0.f, 0.f};
      acc0 = __builtin_amdgcn_mfma_f32_16x16x32_f16(a00, b0, acc0, 0, 0, 0);
      acc0 = __builtin_amdgcn_mfma_f32_16x16x32_f16(a01, b1, acc0, 0, 0, 0);
      acc1 = __builtin_amdgcn_mfma_f32_16x16x32_f16(a10, b0, acc1, 0, 0, 0);
      acc1 = __builtin_amdgcn_mfma_f32_16x16x32_f16(a11, b1, acc1, 0, 0, 0);
#pragma unroll
      for (int i = 0; i < 4; ++i) {
        s[i]     += ex2(fmaf(acc0[i], LOG2E, bo));
        s[4 + i] += ex2(fmaf(acc1[i], LOG2E, bo));
      }
      if (ct + 1 < ct1) { b0 = nb0; b1 = nb1; bo = nbo; }
    }

    // reduce across the 16 lanes (lm) sharing each row
#pragma unroll
    for (int m = 1; m < 16; m <<= 1) {
#pragma unroll
      for (int i = 0; i < 8; ++i) s[i] += __shfl_xor(s[i], m, 64);
    }
    // D-layout: lane holds rows q*4+i (tile0) / 16+q*4+i (tile1)
    if (lm == 0) {
#pragma unroll
      for (int i = 0; i < 4; ++i) {
        spart[wv][q * 4 + i]      = s[i];
        spart[wv][16 + q * 4 + i] = s[4 + i];
      }
    }
  }
  __syncthreads();

  float nll = 0.f;
  if (active && threadIdx.x < 32) {
    const int t = t0 + threadIdx.x;
    if (t < nst) {
      float ssum = 0.f;
#pragma unroll
      for (int c = 0; c < CSPLIT; ++c) ssum += spart[c][threadIdx.x];
      const int col = seq[b * SEQ_STRIDE + t + 1];
      // target logit from the SAME f16 operands (consistent cancellation)
      const unsigned short* xr = Xh + ((size_t)b * LMAXT + t) * HD;
      const unsigned short* wc = Wh + (size_t)(col >> 4) * 1024 + (col & 15) * 64;
      float tl = b_out[col];
#pragma unroll 16
      for (int k = 0; k < 64; ++k)
        tl = fmaf(h2f(xr[k]), h2f(wc[k]), tl);
      nll = (30.f + __logf(ssum)) - tl;
    }
  }
  if (threadIdx.x < 64) {
#pragma unroll
    for (int off = 32; off; off >>= 1) nll += __shfl_down(nll, off, 64);
    if (threadIdx.x == 0) atomicAdd(loss_accum, nll);
  }

  // ---- fused finalize: last of the 640 blocks writes out ----
  __threadfence();
  if (threadIdx.x == 0) lastblk = (atomicAdd(ticket, 1) == NBLK_PROJ - 1);
  __syncthreads();
  if (lastblk && threadIdx.x < 64) {
    float c = (float)steps[threadIdx.x];   // NB == 64
#pragma unroll
    for (int off = 32; off; off >>= 1) c += __shfl_down(c, off, 64);
    if (threadIdx.x == 0) {
      __threadfence();
      out[0] = *(volatile float*)loss_accum / c;
    }
  }
}

// ---------------------------------------------------------------------------
extern "C" void kernel_launch(void* const* d_in, const int* in_sizes, int n_in,
                              void* d_out, int out_size, void* d_ws,
                              size_t ws_size, hipStream_t stream) {
  const float* embeds  = (const float*)d_in[0];
  const float* true_fp = (const float*)d_in[1];
  const int*   perm    = (const int*)d_in[5];
  const float* W_ih    = (const float*)d_in[6];
  const float* b_ih    = (const float*)d_in[7];
  const float* W_hh    = (const float*)d_in[8];
  const float* b_hh    = (const float*)d_in[9];
  const float* W_out   = (const float*)d_in[10];
  const float* b_out   = (const float*)d_in[11];

  char*  ws     = (char*)d_ws;
  int*   seq    = (int*)(ws + SEQ_OFF);
  int*   steps  = (int*)(ws + STEPS_OFF);
  float* loss   = (float*)(ws + LOSS_OFF);
  int*   ticket = (int*)(ws + TICKET_OFF);
  unsigned short* Xh = (unsigned short*)(ws + XB_OFF);
  unsigned short* Wh = (unsigned short*)(ws + WB_OFF);
  float* bo2    = (float*)(ws + BO_OFF);
  float* out    = (float*)d_out;

  k_setup_prep<<<NB + NTILE, 256, 0, stream>>>(
      true_fp, perm, W_out, b_out, seq, steps, Wh, bo2, loss, ticket);
  k_gru<<<NB, 64, 0, stream>>>(embeds, W_ih, b_ih, W_hh, b_hh, seq, steps, Xh);
  k_proj<<<NBLK_PROJ, 512, 0, stream>>>(
      Xh, Wh, bo2, seq, steps, b_out, loss, ticket, out);
}

// Round 12
// 232.501 us; speedup vs baseline: 1.2317x; 1.2317x over previous
//
#include <hip/hip_runtime.h>
#include <hip/hip_fp16.h>
#include <cstdint>
#include <cstddef>

// Problem constants (fixed by reference)
#define NB      64      // batch
#define NBITS   4096
#define HD      64      // hidden
#define IN_DIM  4098
#define LMAXT   320
#define SEQ_STRIDE 336  // padded seq row (>= LMAX+2, mult of 16)
#define NTILE   257     // col tiles of 16 (4112 padded cols)
#define LOG2E   1.44269504088896340f
#define TWO_L2E 2.88539008177792680f
#define CSPLIT  8       // column-split waves per k_proj block
#define NBLK_PROJ 640

// Workspace layout (bytes)
static constexpr size_t SEQ_OFF    = 0;                              // 86016
static constexpr size_t STEPS_OFF  = 86016;                          // 256
static constexpr size_t LOSS_OFF   = 86272;                          // 4
static constexpr size_t XB_OFF     = 86528;                          // 64*320*64*2
static constexpr size_t WB_OFF     = XB_OFF + 2621440;               // 257*1024*2
static constexpr size_t BO_OFF     = WB_OFF + 526336;                // 4112*4

typedef float     f32x4  __attribute__((ext_vector_type(4)));
typedef _Float16  h2     __attribute__((ext_vector_type(2)));
typedef _Float16  h8     __attribute__((ext_vector_type(8)));

#if __has_builtin(__builtin_amdgcn_fdot2)
#define FDOT2(a, b, c) __builtin_amdgcn_fdot2((a), (b), (c), false)
#else
#define FDOT2(a, b, c) fmaf((float)(a)[0], (float)(b)[0], \
                        fmaf((float)(a)[1], (float)(b)[1], (c)))
#endif

// glibc's math.h macro-expands a declaration named __exp2f -> do NOT use that
// identifier; go straight to the HW builtin (v_exp_f32).
__device__ __forceinline__ float ex2(float x) {
#if __has_builtin(__builtin_amdgcn_exp2f)
  return __builtin_amdgcn_exp2f(x);
#else
  return __expf(x * 0.6931471805599453f);
#endif
}
__device__ __forceinline__ float frcp(float x) {
#if __has_builtin(__builtin_amdgcn_rcpf)
  return __builtin_amdgcn_rcpf(x);
#else
  return 1.f / x;
#endif
}

__device__ __forceinline__ unsigned short f2h(float f) {
  return __builtin_bit_cast(unsigned short, (_Float16)f);
}
__device__ __forceinline__ float h2f(unsigned short u) {
  return (float)__builtin_bit_cast(_Float16, u);
}
__device__ __forceinline__ h8 ldh8(const unsigned short* p) {
  return *(const h8*)p;
}
__device__ __forceinline__ void wave_lds_fence() {
  __asm__ __volatile__("s_waitcnt lgkmcnt(0)" ::: "memory");
}

// ---------------------------------------------------------------------------
// Kernel A (merged): blocks 0..63 = per-row compaction (wave 0 only);
// blocks 64..320 = f16 fragment-major W tiles + pre-scaled shifted bias.
// Block 0 also zeroes the loss accumulator.
// ---------------------------------------------------------------------------
__global__ __launch_bounds__(256) void k_setup_prep(
    const float* __restrict__ true_fp, const int* __restrict__ perm,
    const float* __restrict__ W_out, const float* __restrict__ b_out,
    int* __restrict__ seq, int* __restrict__ steps,
    unsigned short* __restrict__ Wh, float* __restrict__ bo2,
    float* __restrict__ loss_accum) {
  __shared__ unsigned long long bits[64];
  const int blk = blockIdx.x;

  if (blk < NB) {
    // ---- compaction for batch row blk (single wave) ----
    if (threadIdx.x >= 64) return;
    const int b = blk;
    const int j = threadIdx.x;
    if (b == 0 && j == 0) *loss_accum = 0.f;
    const float* row = true_fp + (size_t)b * NBITS;
    {
      const float4* rv = (const float4*)(row + j * 64);
      unsigned long long w = 0ull;
#pragma unroll
      for (int i = 0; i < 16; ++i) {
        const float4 v = rv[i];
        w |= (unsigned long long)(v.x > 0.f) << (4 * i + 0);
        w |= (unsigned long long)(v.y > 0.f) << (4 * i + 1);
        w |= (unsigned long long)(v.z > 0.f) << (4 * i + 2);
        w |= (unsigned long long)(v.w > 0.f) << (4 * i + 3);
      }
      bits[j] = w;
    }
    wave_lds_fence();

    int* srow = seq + b * SEQ_STRIDE;
    int base = 0;
    for (int c0 = 0; c0 < IN_DIM; c0 += 64) {
      const int col = c0 + j;
      bool pred = false;
      if (col < IN_DIM) {
        if (col == 0 || col == IN_DIM - 1) pred = true;
        else {
          const int p = perm[col - 1];
          pred = (bits[p >> 6] >> (p & 63)) & 1ull;
        }
      }
      const unsigned long long mask = __ballot(pred);
      const int prefix = __popcll(mask & ((1ull << j) - 1ull));
      const int idx = base + prefix;
      if (pred && idx <= LMAXT) srow[idx] = col;
      base += __popcll(mask);
    }
    const int cap = (base <= LMAXT + 1) ? base : (LMAXT + 1);
    for (int i = cap + j; i < SEQ_STRIDE; i += 64) srow[i] = 0;
    if (j == 0) {
      int s = base - 1;
      if (s > LMAXT) s = LMAXT;
      steps[b] = s;
    }
  } else {
    // ---- W tile prep for col tile c ----
    const int c = blk - NB;              // 0..256
    const int t = threadIdx.x;
    const int m = t & 15;                // col within tile
    const int col = c * 16 + m;
    const bool cok = col < IN_DIM;
#pragma unroll
    for (int kp = 0; kp < 4; ++kp) {
      const int k = kp * 16 + (t >> 4);
      const float v = cok ? W_out[(size_t)k * IN_DIM + col] : 0.f;
      Wh[c * 1024 + m * 64 + k] = f2h(v);
    }
    if (t < 16) {
      const int cc = c * 16 + t;
      bo2[c * 16 + t] = (cc < IN_DIM) ? (b_out[cc] - 30.f) * LOG2E : -1e30f;
    }
  }
}

// ---------------------------------------------------------------------------
// Kernel B: GRU recurrence. ONE WAVE per batch row (R11 version, unchanged).
// ---------------------------------------------------------------------------
#define W_DEF(i) h2 wr##i, wz##i, wn##i;
#define W_INIT(i) {                                                  \
    const float* w0_ = W_hh + (size_t)(2 * (i)) * 192;               \
    const float* w1_ = W_hh + (size_t)(2 * (i) + 1) * 192;           \
    wr##i[0] = (_Float16)w0_[g];       wr##i[1] = (_Float16)w1_[g];  \
    wz##i[0] = (_Float16)w0_[64 + g];  wz##i[1] = (_Float16)w1_[64 + g]; \
    wn##i[0] = (_Float16)w0_[128 + g]; wn##i[1] = (_Float16)w1_[128 + g]; }

#define DOT8(i) {                                                         \
    const h8 v_ = hp8[i];                                                 \
    const h2 e0_ = __builtin_shufflevector(v_, v_, 0, 1);                 \
    const h2 e1_ = __builtin_shufflevector(v_, v_, 2, 3);                 \
    const h2 e2_ = __builtin_shufflevector(v_, v_, 4, 5);                 \
    const h2 e3_ = __builtin_shufflevector(v_, v_, 6, 7);                 \
    sr0 = FDOT2(e0_, wr##i##_0, sr0);  sr1 = FDOT2(e1_, wr##i##_1, sr1);  \
    sr0 = FDOT2(e2_, wr##i##_2, sr0);  sr1 = FDOT2(e3_, wr##i##_3, sr1);  \
    sz0 = FDOT2(e0_, wz##i##_0, sz0);  sz1 = FDOT2(e1_, wz##i##_1, sz1);  \
    sz0 = FDOT2(e2_, wz##i##_2, sz0);  sz1 = FDOT2(e3_, wz##i##_3, sz1);  \
    sn0 = FDOT2(e0_, wn##i##_0, sn0);  sn1 = FDOT2(e1_, wn##i##_1, sn1);  \
    sn0 = FDOT2(e2_, wn##i##_2, sn0);  sn1 = FDOT2(e3_, wn##i##_3, sn1); }

#define W_ALIAS(i8, a, b, c, d)                                           \
  const h2 wr##i8##_0 = wr##a, wr##i8##_1 = wr##b,                        \
           wr##i8##_2 = wr##c, wr##i8##_3 = wr##d;                        \
  const h2 wz##i8##_0 = wz##a, wz##i8##_1 = wz##b,                        \
           wz##i8##_2 = wz##c, wz##i8##_3 = wz##d;                        \
  const h2 wn##i8##_0 = wn##a, wn##i8##_1 = wn##b,                        \
           wn##i8##_2 = wn##c, wn##i8##_3 = wn##d;

__global__ __launch_bounds__(64)
__attribute__((amdgpu_waves_per_eu(1, 1)))
void k_gru(
    const float* __restrict__ embeds,
    const float* __restrict__ W_ih, const float* __restrict__ b_ih,
    const float* __restrict__ W_hh, const float* __restrict__ b_hh,
    const int* __restrict__ seq, const int* __restrict__ steps,
    unsigned short* __restrict__ Xh) {
  const int b = blockIdx.x;
  const int g = threadIdx.x;   // 0..63

  __shared__ __align__(16) _Float16 hl[HD];
  __shared__ int seqL[LMAXT + 2];
  for (int i = g; i < LMAXT + 2; i += 64) seqL[i] = seq[b * SEQ_STRIDE + i];

  W_DEF(0)  W_DEF(1)  W_DEF(2)  W_DEF(3)  W_DEF(4)  W_DEF(5)  W_DEF(6)  W_DEF(7)
  W_DEF(8)  W_DEF(9)  W_DEF(10) W_DEF(11) W_DEF(12) W_DEF(13) W_DEF(14) W_DEF(15)
  W_DEF(16) W_DEF(17) W_DEF(18) W_DEF(19) W_DEF(20) W_DEF(21) W_DEF(22) W_DEF(23)
  W_DEF(24) W_DEF(25) W_DEF(26) W_DEF(27) W_DEF(28) W_DEF(29) W_DEF(30) W_DEF(31)
  W_INIT(0)  W_INIT(1)  W_INIT(2)  W_INIT(3)  W_INIT(4)  W_INIT(5)  W_INIT(6)  W_INIT(7)
  W_INIT(8)  W_INIT(9)  W_INIT(10) W_INIT(11) W_INIT(12) W_INIT(13) W_INIT(14) W_INIT(15)
  W_INIT(16) W_INIT(17) W_INIT(18) W_INIT(19) W_INIT(20) W_INIT(21) W_INIT(22) W_INIT(23)
  W_INIT(24) W_INIT(25) W_INIT(26) W_INIT(27) W_INIT(28) W_INIT(29) W_INIT(30) W_INIT(31)
  W_ALIAS(0, 0, 1, 2, 3)     W_ALIAS(1, 4, 5, 6, 7)
  W_ALIAS(2, 8, 9, 10, 11)   W_ALIAS(3, 12, 13, 14, 15)
  W_ALIAS(4, 16, 17, 18, 19) W_ALIAS(5, 20, 21, 22, 23)
  W_ALIAS(6, 24, 25, 26, 27) W_ALIAS(7, 28, 29, 30, 31)

  // pre-scaled bias terms (fold bias + log2e scale into the prefetch fma)
  const float br2  = (b_ih[g]       + b_hh[g])       * -LOG2E;
  const float bz2  = (b_ih[64 + g]  + b_hh[64 + g])  * -LOG2E;
  const float bn2  = b_ih[128 + g]  * TWO_L2E;
  const float bhn2 = b_hh[128 + g]  * TWO_L2E;
  const int nst = steps[b];

  float hself = embeds[b * HD + g];
  hl[g] = (_Float16)hself;

  unsigned short* xptr = Xh + (size_t)b * LMAXT * HD + g;

  // depth-4 named prefetch slots: pre-scaled W_ih contributions
  float p0r, p0z, p0n, p1r, p1z, p1n, p2r, p2z, p2n, p3r, p3z, p3n;
  {
    const float* r0 = W_ih + (size_t)seqL[0] * 192;
    p0r = fmaf(r0[g], -LOG2E, br2); p0z = fmaf(r0[64 + g], -LOG2E, bz2);
    p0n = fmaf(r0[128 + g], TWO_L2E, bn2);
    const float* r1 = W_ih + (size_t)seqL[1] * 192;
    p1r = fmaf(r1[g], -LOG2E, br2); p1z = fmaf(r1[64 + g], -LOG2E, bz2);
    p1n = fmaf(r1[128 + g], TWO_L2E, bn2);
    const float* r2 = W_ih + (size_t)seqL[2] * 192;
    p2r = fmaf(r2[g], -LOG2E, br2); p2z = fmaf(r2[64 + g], -LOG2E, bz2);
    p2n = fmaf(r2[128 + g], TWO_L2E, bn2);
    const float* r3 = W_ih + (size_t)seqL[3] * 192;
    p3r = fmaf(r3[g], -LOG2E, br2); p3z = fmaf(r3[64 + g], -LOG2E, bz2);
    p3n = fmaf(r3[128 + g], TWO_L2E, bn2);
  }

#define GSTEP(u) {                                                        \
    int nt_ = t + (u) + 4; nt_ = (nt_ <= LMAXT + 1) ? nt_ : (LMAXT + 1);  \
    const int sidx_ = seqL[nt_];                                          \
    const h8* hp8 = (const h8*)hl;                                        \
    float sr0 = 0.f, sr1 = 0.f, sz0 = 0.f, sz1 = 0.f, sn0 = 0.f, sn1 = 0.f; \
    DOT8(0) DOT8(1) DOT8(2) DOT8(3) DOT8(4) DOT8(5) DOT8(6) DOT8(7)       \
    const float rr = frcp(1.f + ex2(fmaf(sr0 + sr1, -LOG2E, p##u##r)));   \
    const float zz = frcp(1.f + ex2(fmaf(sz0 + sz1, -LOG2E, p##u##z)));   \
    const float g2 = fmaf(sn0 + sn1, TWO_L2E, bhn2);                      \
    const float q  = frcp(1.f + ex2(fmaf(rr, g2, p##u##n)));              \
    const float th = fmaf(-2.f, q, 1.f);                                  \
    const float hn = fmaf(zz, hself - th, th);                            \
    hself = hn;                                                           \
    const _Float16 hh = (_Float16)hn;                                     \
    hl[g] = hh;                                                           \
    xptr[(size_t)(t + (u)) * HD] = __builtin_bit_cast(unsigned short, hh);\
    const float* rw_ = W_ih + (size_t)sidx_ * 192;                        \
    p##u##r = fmaf(rw_[g], -LOG2E, br2);                                  \
    p##u##z = fmaf(rw_[64 + g], -LOG2E, bz2);                             \
    p##u##n = fmaf(rw_[128 + g], TWO_L2E, bn2); }

  const int ngroups = (nst + 3) >> 2;
  for (int tg = 0; tg < ngroups; ++tg) {
    const int t = tg * 4;
    GSTEP(0)
    GSTEP(1)
    GSTEP(2)
    GSTEP(3)
  }
#undef GSTEP

  // zero-fill padded rows (overwrites the <=3 garbage tail stores too)
  for (int i = nst * HD + g; i < LMAXT * HD; i += 64)
    Xh[(size_t)b * (LMAXT * HD) + i] = 0;
}

// ---------------------------------------------------------------------------
// Kernel C: MFMA f16 fused projection + logsumexp + NLL.
// R11 post-mortem: compiler allocated VGPR=32 and SPILLED the MFMA operands
// (MfmaUtil 2.6%, 106us). Fix: amdgpu_waves_per_eu(4,8) -> VGPR cap 128,
// allocator keeps the ~60-80 live values in registers; finalize moved back
// to its own kernel (no device fence in 640 blocks).
// ---------------------------------------------------------------------------
__global__ __launch_bounds__(512)
__attribute__((amdgpu_waves_per_eu(4, 8)))
void k_proj(
    const unsigned short* __restrict__ Xh,
    const unsigned short* __restrict__ Wh,
    const float* __restrict__ bo2,
    const int* __restrict__ seq, const int* __restrict__ steps,
    const float* __restrict__ b_out,
    float* __restrict__ loss_accum) {
  const int l  = threadIdx.x & 63;
  const int wv = threadIdx.x >> 6;         // 0..7 column-split wave id
  const int b  = blockIdx.x / 10;
  const int t0 = (blockIdx.x % 10) * 32;
  const int nst = steps[b];
  const bool active = (t0 < nst);          // block-uniform

  __shared__ float spart[CSPLIT][32];

  if (active) {
    const int lm = l & 15;
    const int q  = l >> 4;

    const unsigned short* xp0 = Xh + ((size_t)b * LMAXT + t0 + lm) * HD + q * 8;
    const h8 a00 = ldh8(xp0);
    const h8 a01 = ldh8(xp0 + 32);
    const h8 a10 = ldh8(xp0 + 16 * HD);
    const h8 a11 = ldh8(xp0 + 16 * HD + 32);

    float s[8];
#pragma unroll
    for (int i = 0; i < 8; ++i) s[i] = 0.f;

    const int ct0 = wv * 33;
    const int ct1 = (ct0 + 33 < NTILE) ? (ct0 + 33) : NTILE;   // wave 7: 26

    const unsigned short* wp = Wh + lm * 64 + q * 8;
    const float* bop = bo2 + lm;

    h8 b0 = ldh8(wp + (size_t)ct0 * 1024);
    h8 b1 = ldh8(wp + (size_t)ct0 * 1024 + 32);
    float bo = bop[ct0 * 16];
    for (int ct = ct0; ct < ct1; ++ct) {
      h8 nb0, nb1; float nbo;
      if (ct + 1 < ct1) {
        const unsigned short* wpn = wp + (size_t)(ct + 1) * 1024;
        nb0 = ldh8(wpn); nb1 = ldh8(wpn + 32); nbo = bop[(ct + 1) * 16];
      }
      f32x4 acc0 = {0.f, 0.f, 0.f, 0.f};
      f32x4 acc1 = {0.f, 0.f, 0.f, 0.f};
      acc0 = __builtin_amdgcn_mfma_f32_16x16x32_f16(a00, b0, acc0, 0, 0, 0);
      acc0 = __builtin_amdgcn_mfma_f32_16x16x32_f16(a01, b1, acc0, 0, 0, 0);
      acc1 = __builtin_amdgcn_mfma_f32_16x16x32_f16(a10, b0, acc1, 0, 0, 0);
      acc1 = __builtin_amdgcn_mfma_f32_16x16x32_f16(a11, b1, acc1, 0, 0, 0);
#pragma unroll
      for (int i = 0; i < 4; ++i) {
        s[i]     += ex2(fmaf(acc0[i], LOG2E, bo));
        s[4 + i] += ex2(fmaf(acc1[i], LOG2E, bo));
      }
      if (ct + 1 < ct1) { b0 = nb0; b1 = nb1; bo = nbo; }
    }

    // reduce across the 16 lanes (lm) sharing each row
#pragma unroll
    for (int m = 1; m < 16; m <<= 1) {
#pragma unroll
      for (int i = 0; i < 8; ++i) s[i] += __shfl_xor(s[i], m, 64);
    }
    // D-layout: lane holds rows q*4+i (tile0) / 16+q*4+i (tile1)
    if (lm == 0) {
#pragma unroll
      for (int i = 0; i < 4; ++i) {
        spart[wv][q * 4 + i]      = s[i];
        spart[wv][16 + q * 4 + i] = s[4 + i];
      }
    }
  }
  __syncthreads();

  float nll = 0.f;
  if (active && threadIdx.x < 32) {
    const int t = t0 + threadIdx.x;
    if (t < nst) {
      float ssum = 0.f;
#pragma unroll
      for (int c = 0; c < CSPLIT; ++c) ssum += spart[c][threadIdx.x];
      const int col = seq[b * SEQ_STRIDE + t + 1];
      // target logit from the SAME f16 operands (consistent cancellation)
      const unsigned short* xr = Xh + ((size_t)b * LMAXT + t) * HD;
      const unsigned short* wc = Wh + (size_t)(col >> 4) * 1024 + (col & 15) * 64;
      float tl = b_out[col];
#pragma unroll 16
      for (int k = 0; k < 64; ++k)
        tl = fmaf(h2f(xr[k]), h2f(wc[k]), tl);
      nll = (30.f + __logf(ssum)) - tl;
    }
  }
  if (threadIdx.x < 64) {
#pragma unroll
    for (int off = 32; off; off >>= 1) nll += __shfl_down(nll, off, 64);
    if (threadIdx.x == 0) atomicAdd(loss_accum, nll);
  }
}

// ---------------------------------------------------------------------------
// Kernel D: finalize (loss_sum / count).
// ---------------------------------------------------------------------------
__global__ void k_final(const float* __restrict__ loss_accum,
                        const int* __restrict__ steps,
                        float* __restrict__ out) {
  if (threadIdx.x == 0 && blockIdx.x == 0) {
    int cnt = 0;
    for (int i = 0; i < NB; ++i) cnt += steps[i];
    out[0] = loss_accum[0] / (float)cnt;
  }
}

// ---------------------------------------------------------------------------
extern "C" void kernel_launch(void* const* d_in, const int* in_sizes, int n_in,
                              void* d_out, int out_size, void* d_ws,
                              size_t ws_size, hipStream_t stream) {
  const float* embeds  = (const float*)d_in[0];
  const float* true_fp = (const float*)d_in[1];
  const int*   perm    = (const int*)d_in[5];
  const float* W_ih    = (const float*)d_in[6];
  const float* b_ih    = (const float*)d_in[7];
  const float* W_hh    = (const float*)d_in[8];
  const float* b_hh    = (const float*)d_in[9];
  const float* W_out   = (const float*)d_in[10];
  const float* b_out   = (const float*)d_in[11];

  char*  ws     = (char*)d_ws;
  int*   seq    = (int*)(ws + SEQ_OFF);
  int*   steps  = (int*)(ws + STEPS_OFF);
  float* loss   = (float*)(ws + LOSS_OFF);
  unsigned short* Xh = (unsigned short*)(ws + XB_OFF);
  unsigned short* Wh = (unsigned short*)(ws + WB_OFF);
  float* bo2    = (float*)(ws + BO_OFF);
  float* out    = (float*)d_out;

  k_setup_prep<<<NB + NTILE, 256, 0, stream>>>(
      true_fp, perm, W_out, b_out, seq, steps, Wh, bo2, loss);
  k_gru<<<NB, 64, 0, stream>>>(embeds, W_ih, b_ih, W_hh, b_hh, seq, steps, Xh);
  k_proj<<<NBLK_PROJ, 512, 0, stream>>>(
      Xh, Wh, bo2, seq, steps, b_out, loss);
  k_final<<<1, 64, 0, stream>>>(loss, steps, out);
}